// Round 4
// baseline (3397.220 us; speedup 1.0000x reference)
//
#include <hip/hip_runtime.h>

// GATRNN: T=12 steps of {GAT1(inputs_t) -> GRU -> GAT2}, then Linear(H->D).
// fp32 I/O. Graph hardcoded: edge k: sender=k/63, receiver=k%63; node 63 inert.
// R4: per-batch persistent blocks (grid 32, block 1024) — the T-loop runs
// entirely in one block per batch with h in LDS (no grid barriers, no in-loop
// global writes). gi = x@Wih^T+bih hoisted to a full-GPU precompute kernel.
// In-loop weights read with wave-uniform addresses (lane=row mapping).

#define T_   12
#define B_   32
#define N_   64
#define D_   2
#define H_   128
#define HID_ 32
#define HEAD_ 4
#define NA_  63
#define SHP  129   // padded row stride for [64][128] LDS tiles (bank-conflict-free)

__device__ __forceinline__ float eluf(float x){ return x>0.f ? x : expm1f(x); }

// ---- ws layout (floats) ----
#define OFF_X1  0u           // T*B*N*HID          = 786432
#define OFF_PS1 786432u      // T*B*N*HEAD         =  98304
#define OFF_PR1 884736u      //                    =  98304
#define OFF_XG  983040u      // T*B*N*H            = 3145728
#define OFF_GI  4128768u     // T*B*384*64         = 9437184  (layout [t][b][j][r])
// end = 13565952 floats = 51.8 MB

// ---------------- GAT1 fc1 + edge projections, grid T*B x 256 ----------------
__global__ void gat1_fc(const float* __restrict__ inp, const float* __restrict__ W1,
                        const float* __restrict__ b1, const float* __restrict__ W2,
                        const float* __restrict__ b2,
                        float* __restrict__ x1_all, float* __restrict__ ps_all,
                        float* __restrict__ pr_all){
  int grp = blockIdx.x;
  int tid = threadIdx.x;
  __shared__ float sx1[N_*HID_];
  __shared__ float sW1[HID_*D_];
  __shared__ float sb1[HID_];
  __shared__ float sW2[HEAD_*2*HID_];
  __shared__ float sxin[N_*D_];
  if(tid < 64)  sW1[tid] = W1[tid];
  if(tid < 32)  sb1[tid] = b1[tid];
  sW2[tid] = W2[tid];
  if(tid < 128) sxin[tid] = inp[grp*N_*D_ + tid];
  __syncthreads();
  for(int o = tid; o < N_*HID_; o += 256){
    int n = o >> 5, k = o & 31;
    float v = sb1[k] + sxin[n*2]*sW1[k*2] + sxin[n*2+1]*sW1[k*2+1];
    sx1[o] = v;
    x1_all[grp*N_*HID_ + o] = v;
  }
  __syncthreads();
  for(int p = tid; p < N_*8; p += 256){
    int n = p >> 3, q = p & 7, hh = q & 3;
    const float* w  = sW2 + hh*64 + ((q < 4) ? 0 : 32);
    const float* xr = sx1 + n*32;
    float acc = (q < 4) ? b2[hh] : 0.f;
    #pragma unroll
    for(int c = 0; c < 32; c++) acc += xr[c]*w[c];
    if(q < 4) ps_all[grp*N_*HEAD_ + n*4 + hh] = acc;
    else      pr_all[grp*N_*HEAD_ + n*4 + hh] = acc;
  }
}

// ---------------- attention subgroup (32 lanes, one receiver) ----------------
__device__ __forceinline__ void att_subgroup(
    const float* sx2, const float* sps, float* se_sg, float* ss_sg,
    float prj, int l, float* orow){
  int hh = l & 3, i0 = l >> 2;
  float pmax = -1e30f;
  #pragma unroll
  for(int k = 0; k < 8; k++){
    int i = i0 + 8*k;
    if(i < NA_){
      float v = eluf(sps[i*4 + hh] + prj);
      se_sg[i*4 + hh] = v;
      pmax = fmaxf(pmax, v);
    }
  }
  #pragma unroll
  for(int st = 4; st < 32; st <<= 1) pmax = fmaxf(pmax, __shfl_xor(pmax, st, 32));
  float psum = 0.f;
  #pragma unroll
  for(int k = 0; k < 8; k++){
    int i = i0 + 8*k;
    if(i < NA_){
      float e = expf(se_sg[i*4 + hh] - pmax);
      se_sg[i*4 + hh] = e;
      psum += e;
    }
  }
  #pragma unroll
  for(int st = 4; st < 32; st <<= 1) psum += __shfl_xor(psum, st, 32);
  if(i0 == 0) ss_sg[hh] = psum;
  float a0=0.f, a1=0.f, a2=0.f, a3=0.f;
  for(int i = 0; i < NA_; i++){
    float4 e4 = *(const float4*)&se_sg[i*4];
    float xv = sx2[i*32 + l];
    a0 += e4.x*xv; a1 += e4.y*xv; a2 += e4.z*xv; a3 += e4.w*xv;
  }
  orow[l]      = eluf(a0 / ss_sg[0]);
  orow[32 + l] = eluf(a1 / ss_sg[1]);
  orow[64 + l] = eluf(a2 / ss_sg[2]);
  orow[96 + l] = eluf(a3 / ss_sg[3]);
}

// GAT1 attention: 8 receivers per block. grid = T*B*8 x 256. writes xg_all.
__global__ __launch_bounds__(256) void att8(const float* __restrict__ x1,
                                            const float* __restrict__ ps,
                                            const float* __restrict__ pr,
                                            float* __restrict__ out){
  __shared__ float smem[4384];
  float* sx2 = smem;
  float* sps = smem + 2048;
  float* se  = smem + 2304;
  float* ss  = smem + 4352;
  int blk = blockIdx.x, tid = threadIdx.x;
  int grp = blk >> 3;
  const float* x1g = x1 + (size_t)grp * (N_*HID_);
  const float* psg = ps + (size_t)grp * (N_*HEAD_);
  for(int i = tid; i < NA_*HID_; i += 256) sx2[i] = x1g[i];
  for(int i = tid; i < NA_*HEAD_; i += 256) sps[i] = psg[i];
  __syncthreads();
  int sg = tid >> 5, l = tid & 31;
  int idx = blk*8 + sg, j = idx & 63;
  float* orow = out + (size_t)idx * H_;
  if(j == NA_){
    #pragma unroll
    for(int q = 0; q < 4; q++) orow[q*32 + l] = 0.f;
    return;
  }
  float prj = pr[(size_t)idx*4 + (l & 3)];
  att_subgroup(sx2, sps, se + sg*256, ss + sg*4, prj, l, orow);
}

// gi = xg @ Wih^T + bih, stored transposed: gi[t][b][j][r]. grid T*B x 1024.
__global__ __launch_bounds__(1024) void gi_k(const float* __restrict__ xg,
                                             const float* __restrict__ Wih,
                                             const float* __restrict__ bih,
                                             float* __restrict__ gi){
  __shared__ float sxg[64*SHP];
  int tb = blockIdx.x;
  int tid = threadIdx.x;
  const float* xr = xg + (size_t)tb*(N_*H_);
  for(int i = tid; i < N_*H_; i += 1024){
    int r = i >> 7, k = i & 127;
    sxg[r*SHP + k] = xr[i];
  }
  __syncthreads();
  int r = tid & 63;
  int grpu = __builtin_amdgcn_readfirstlane(tid >> 6);   // wave-uniform 0..15
  const float* w0 = Wih + (size_t)(      grpu*8)*H_;
  const float* w1 = Wih + (size_t)(128 + grpu*8)*H_;
  const float* w2 = Wih + (size_t)(256 + grpu*8)*H_;
  float acc[8][3];
  #pragma unroll
  for(int cc = 0; cc < 8; cc++){
    acc[cc][0] = bih[      grpu*8+cc];
    acc[cc][1] = bih[128 + grpu*8+cc];
    acc[cc][2] = bih[256 + grpu*8+cc];
  }
  for(int kc = 0; kc < 8; kc++){
    float hv[16];
    #pragma unroll
    for(int k = 0; k < 16; k++) hv[k] = sxg[r*SHP + kc*16 + k];
    #pragma unroll
    for(int cc = 0; cc < 8; cc++){
      #pragma unroll
      for(int k = 0; k < 16; k++){
        float x = hv[k];
        acc[cc][0] += w0[cc*H_ + kc*16 + k]*x;
        acc[cc][1] += w1[cc*H_ + kc*16 + k]*x;
        acc[cc][2] += w2[cc*H_ + kc*16 + k]*x;
      }
    }
  }
  float* go = gi + (size_t)tb*384*64;
  #pragma unroll
  for(int cc = 0; cc < 8; cc++){
    int c = grpu*8 + cc;
    go[(      c)*64 + r] = acc[cc][0];
    go[(128 + c)*64 + r] = acc[cc][1];
    go[(256 + c)*64 + r] = acc[cc][2];
  }
}

// ---------------- persistent per-batch T-loop. grid 32 x 1024 ----------------
__global__ __launch_bounds__(1024) void loop_k(
    const float* __restrict__ gi_all, const float* __restrict__ h0,
    const float* __restrict__ Whh, const float* __restrict__ bhh,
    const float* __restrict__ W1, const float* __restrict__ b1,
    const float* __restrict__ W2, const float* __restrict__ b2,
    const float* __restrict__ oW, const float* __restrict__ ob,
    float* __restrict__ pred){
  __shared__ float sh[64*SHP];     // h (persists across steps)
  __shared__ float sx2[64*33];     // GAT2 fc1 out (senders)
  __shared__ float sef[64*4];      // ps (sender proj + b2)
  __shared__ float spr[64*4];      // pr (receiver proj)
  __shared__ float sscr[32*256];   // per-subgroup attention scratch
  __shared__ float sW1[32*H_];
  __shared__ float sW2t[8*33];
  __shared__ float sb1[32], sob[2], soW[2*H_];
  int tid = threadIdx.x, b = blockIdx.x;

  for(int i = tid; i < N_*H_; i += 1024){
    int r = i >> 7, k = i & 127;
    sh[r*SHP + k] = h0[(size_t)b*N_*H_ + i];
  }
  for(int i = tid; i < 32*H_; i += 1024) sW1[i] = W1[i];
  if(tid < 256){
    int q = tid >> 5, cc = tid & 31;
    sW2t[q*33 + cc] = W2[(q&3)*64 + ((q < 4) ? 0 : 32) + cc];
  }
  if(tid < 32) sb1[tid] = b1[tid];
  if(tid < 256) soW[tid] = oW[tid];
  if(tid < 2) sob[tid] = ob[tid];
  __syncthreads();

  int r = tid & 63;
  int grpu = __builtin_amdgcn_readfirstlane(tid >> 6);   // wave-uniform 0..15
  const float* wg0 = Whh + (size_t)(      grpu*8)*H_;
  const float* wg1 = Whh + (size_t)(128 + grpu*8)*H_;
  const float* wg2 = Whh + (size_t)(256 + grpu*8)*H_;
  int sg = tid >> 5, l = tid & 31;

  for(int t = 0; t < T_; t++){
    // ---- phase A: gh = h@Whh^T (lane=row, uniform weight addrs), GRU gates
    const float* gip = gi_all + ((size_t)t*B_ + b)*384*64;
    float gir[8], giz[8], gin[8];
    #pragma unroll
    for(int cc = 0; cc < 8; cc++){
      int c = grpu*8 + cc;
      gir[cc] = gip[(      c)*64 + r];
      giz[cc] = gip[(128 + c)*64 + r];
      gin[cc] = gip[(256 + c)*64 + r];
    }
    float acc[8][3];
    #pragma unroll
    for(int cc = 0; cc < 8; cc++){ acc[cc][0]=0.f; acc[cc][1]=0.f; acc[cc][2]=0.f; }
    for(int kc = 0; kc < 8; kc++){
      float hv[16];
      #pragma unroll
      for(int k = 0; k < 16; k++) hv[k] = sh[r*SHP + kc*16 + k];
      #pragma unroll
      for(int cc = 0; cc < 8; cc++){
        #pragma unroll
        for(int k = 0; k < 16; k++){
          float x = hv[k];
          acc[cc][0] += wg0[cc*H_ + kc*16 + k]*x;
          acc[cc][1] += wg1[cc*H_ + kc*16 + k]*x;
          acc[cc][2] += wg2[cc*H_ + kc*16 + k]*x;
        }
      }
    }
    float hnew[8];
    #pragma unroll
    for(int cc = 0; cc < 8; cc++){
      int c = grpu*8 + cc;
      float hr = acc[cc][0] + bhh[c];
      float hz = acc[cc][1] + bhh[128 + c];
      float hn = acc[cc][2] + bhh[256 + c];
      float hp = sh[r*SHP + c];
      float rg = 1.f/(1.f + expf(-(gir[cc] + hr)));
      float zg = 1.f/(1.f + expf(-(giz[cc] + hz)));
      float ng = tanhf(gin[cc] + rg*hn);
      hnew[cc] = (1.f - zg)*ng + zg*hp;
    }
    __syncthreads();
    #pragma unroll
    for(int cc = 0; cc < 8; cc++) sh[r*SHP + grpu*8 + cc] = hnew[cc];
    __syncthreads();

    // ---- phase B: fc1 (x2 = h@W1^T + b1), then fc2 (ps, pr)
    {
      int jc0 = grpu*2;
      float a0 = sb1[jc0], a1 = sb1[jc0+1];
      #pragma unroll 8
      for(int k = 0; k < H_; k++){
        float hv = sh[r*SHP + k];
        a0 += sW1[ jc0   *H_ + k]*hv;
        a1 += sW1[(jc0+1)*H_ + k]*hv;
      }
      sx2[r*33 + jc0]     = a0;
      sx2[r*33 + jc0 + 1] = a1;
    }
    __syncthreads();
    if(tid < 512){
      int rr = tid >> 3, q = tid & 7, hh = q & 3;
      float a = (q < 4) ? b2[hh] : 0.f;
      #pragma unroll
      for(int cc = 0; cc < 32; cc++) a += sx2[rr*33 + cc]*sW2t[q*33 + cc];
      if(q < 4) sef[rr*4 + hh] = a;
      else      spr[rr*4 + hh] = a;
    }
    __syncthreads();

    // ---- phase C: attention, 2 receivers per 32-lane subgroup, writes h
    float* scr = sscr + sg*256;
    #pragma unroll
    for(int rep = 0; rep < 2; rep++){
      int j = sg*2 + rep;
      if(j == NA_){
        #pragma unroll
        for(int q = 0; q < 4; q++) sh[j*SHP + q*32 + l] = 0.f;
      } else {
        float prj = spr[j*4 + (l & 3)];
        int hh = l & 3, i0 = l >> 2;
        float pmax = -1e30f;
        #pragma unroll
        for(int k = 0; k < 8; k++){
          int i = i0 + 8*k;
          if(i < NA_){
            float v = eluf(sef[i*4 + hh] + prj);
            scr[i*4 + hh] = v;
            pmax = fmaxf(pmax, v);
          }
        }
        #pragma unroll
        for(int st = 4; st < 32; st <<= 1) pmax = fmaxf(pmax, __shfl_xor(pmax, st, 32));
        float psum = 0.f;
        #pragma unroll
        for(int k = 0; k < 8; k++){
          int i = i0 + 8*k;
          if(i < NA_){
            float e = expf(scr[i*4 + hh] - pmax);
            scr[i*4 + hh] = e;
            psum += e;
          }
        }
        #pragma unroll
        for(int st = 4; st < 32; st <<= 1) psum += __shfl_xor(psum, st, 32);
        if(i0 == 0) scr[252 + hh] = psum;
        float a0=0.f, a1=0.f, a2=0.f, a3=0.f;
        for(int i = 0; i < NA_; i++){
          float4 e4 = *(const float4*)&scr[i*4];
          float xv = sx2[i*33 + l];
          a0 += e4.x*xv; a1 += e4.y*xv; a2 += e4.z*xv; a3 += e4.w*xv;
        }
        sh[j*SHP +      l] = eluf(a0/scr[252]);
        sh[j*SHP + 32 + l] = eluf(a1/scr[253]);
        sh[j*SHP + 64 + l] = eluf(a2/scr[254]);
        sh[j*SHP + 96 + l] = eluf(a3/scr[255]);
      }
    }
    __syncthreads();
  }

  // ---- final Linear(H->D)
  if(tid < 128){
    int n = tid >> 1, d = tid & 1;
    float a = sob[d];
    #pragma unroll 8
    for(int k = 0; k < H_; k++) a += sh[n*SHP + k]*soW[d*H_ + k];
    pred[((size_t)b*N_ + n)*D_ + d] = a;
  }
}

extern "C" void kernel_launch(void* const* d_in, const int* in_sizes, int n_in,
                              void* d_out, int out_size, void* d_ws, size_t ws_size,
                              hipStream_t stream){
  const float* inputs = (const float*)d_in[0];
  const float* hidden = (const float*)d_in[1];
  const float* rn1_W1 = (const float*)d_in[4];
  const float* rn1_b1 = (const float*)d_in[5];
  const float* rn1_W2 = (const float*)d_in[6];
  const float* rn1_b2 = (const float*)d_in[7];
  const float* rn2_W1 = (const float*)d_in[8];
  const float* rn2_b1 = (const float*)d_in[9];
  const float* rn2_W2 = (const float*)d_in[10];
  const float* rn2_b2 = (const float*)d_in[11];
  const float* gWih   = (const float*)d_in[12];
  const float* gWhh   = (const float*)d_in[13];
  const float* gbih   = (const float*)d_in[14];
  const float* gbhh   = (const float*)d_in[15];
  const float* oW     = (const float*)d_in[16];
  const float* ob     = (const float*)d_in[17];
  float* ws = (float*)d_ws;

  gat1_fc<<<T_*B_, 256, 0, stream>>>(inputs, rn1_W1, rn1_b1, rn1_W2, rn1_b2,
                                     ws + OFF_X1, ws + OFF_PS1, ws + OFF_PR1);
  att8<<<T_*B_*8, 256, 0, stream>>>(ws + OFF_X1, ws + OFF_PS1, ws + OFF_PR1,
                                    ws + OFF_XG);
  gi_k<<<T_*B_, 1024, 0, stream>>>(ws + OFF_XG, gWih, gbih, ws + OFF_GI);
  loop_k<<<B_, 1024, 0, stream>>>(ws + OFF_GI, hidden,
                                  gWhh, gbhh,
                                  rn2_W1, rn2_b1, rn2_W2, rn2_b2,
                                  oW, ob, (float*)d_out);
}

// Round 5
// 2292.081 us; speedup vs baseline: 1.4822x; 1.4822x over previous
//
#include <hip/hip_runtime.h>

// GATRNN: T=12 steps of {GAT1(inputs_t) -> GRU -> GAT2}, then Linear(H->D).
// fp32 I/O. Graph hardcoded: edge k: sender=k/63, receiver=k%63; node 63 inert.
// R5: per-batch persistent blocks, grid 32 x block 512 (spill-free: ~96 acc
// regs/thread, launch_bounds(512,2) -> 256-VGPR cap). h lives in LDS across
// all 12 steps; no grid barriers; gi = x@Wih^T (+bih +bhr/bhz folded) hoisted.

#define T_   12
#define B_   32
#define N_   64
#define D_   2
#define H_   128
#define HID_ 32
#define HEAD_ 4
#define NA_  63
#define SHP  129   // padded row stride for [64][128] LDS tiles

__device__ __forceinline__ float eluf(float x){ return x>0.f ? x : expm1f(x); }

// ---- ws layout (floats) ----
#define OFF_X1  0u           // T*B*N*HID  = 786432
#define OFF_PS1 786432u      // T*B*N*HEAD =  98304
#define OFF_PR1 884736u      //            =  98304
#define OFF_XG  983040u      // T*B*N*H    = 3145728
#define OFF_GI  4128768u     // T*B*384*64 = 9437184   layout [t][b][c][n]
// end = 13565952 floats = 51.8 MB

// ---------------- GAT1 fc1 + edge projections, grid T*B x 256 ----------------
__global__ __launch_bounds__(256, 4) void gat1_fc(
    const float* __restrict__ inp, const float* __restrict__ W1,
    const float* __restrict__ b1, const float* __restrict__ W2,
    const float* __restrict__ b2,
    float* __restrict__ x1_all, float* __restrict__ ps_all,
    float* __restrict__ pr_all){
  int grp = blockIdx.x;
  int tid = threadIdx.x;
  __shared__ float sx1[N_*HID_];
  __shared__ float sW1[HID_*D_];
  __shared__ float sb1[HID_];
  __shared__ float sW2[HEAD_*2*HID_];
  __shared__ float sxin[N_*D_];
  if(tid < 64)  sW1[tid] = W1[tid];
  if(tid < 32)  sb1[tid] = b1[tid];
  sW2[tid] = W2[tid];
  if(tid < 128) sxin[tid] = inp[grp*N_*D_ + tid];
  __syncthreads();
  for(int o = tid; o < N_*HID_; o += 256){
    int n = o >> 5, k = o & 31;
    float v = sb1[k] + sxin[n*2]*sW1[k*2] + sxin[n*2+1]*sW1[k*2+1];
    sx1[o] = v;
    x1_all[grp*N_*HID_ + o] = v;
  }
  __syncthreads();
  for(int p = tid; p < N_*8; p += 256){
    int n = p >> 3, q = p & 7, hh = q & 3;
    const float* w  = sW2 + hh*64 + ((q < 4) ? 0 : 32);
    const float* xr = sx1 + n*32;
    float acc = (q < 4) ? b2[hh] : 0.f;
    #pragma unroll
    for(int c = 0; c < 32; c++) acc += xr[c]*w[c];
    if(q < 4) ps_all[grp*N_*HEAD_ + n*4 + hh] = acc;
    else      pr_all[grp*N_*HEAD_ + n*4 + hh] = acc;
  }
}

// GAT1 attention: 8 receivers/block (32-lane subgroup each). grid = T*B*8 x 256.
__global__ __launch_bounds__(256, 4) void att8(const float* __restrict__ x1,
                                               const float* __restrict__ ps,
                                               const float* __restrict__ pr,
                                               float* __restrict__ out){
  __shared__ float smem[4384];
  float* sx2 = smem;            // 63*32
  float* sps = smem + 2048;     // 63*4
  float* se  = smem + 2304;     // 8*256
  int blk = blockIdx.x, tid = threadIdx.x;
  int grp = blk >> 3;
  const float* x1g = x1 + (size_t)grp * (N_*HID_);
  const float* psg = ps + (size_t)grp * (N_*HEAD_);
  for(int i = tid; i < NA_*HID_; i += 256) sx2[i] = x1g[i];
  for(int i = tid; i < NA_*HEAD_; i += 256) sps[i] = psg[i];
  __syncthreads();
  int sg = tid >> 5, l = tid & 31;
  int idx = blk*8 + sg, j = idx & 63;
  float* orow = out + (size_t)idx * H_;
  float* scr = se + sg*256;
  if(j == NA_){
    #pragma unroll
    for(int q = 0; q < 4; q++) orow[q*32 + l] = 0.f;
    return;
  }
  float prj = pr[(size_t)idx*4 + (l & 3)];
  int hh = l & 3, i0 = l >> 2;
  float pmax = -1e30f;
  #pragma unroll
  for(int k = 0; k < 8; k++){
    int i = i0 + 8*k;
    if(i < NA_){
      float v = eluf(sps[i*4 + hh] + prj);
      scr[i*4 + hh] = v;
      pmax = fmaxf(pmax, v);
    }
  }
  #pragma unroll
  for(int st = 4; st < 32; st <<= 1) pmax = fmaxf(pmax, __shfl_xor(pmax, st, 32));
  float psum = 0.f;
  #pragma unroll
  for(int k = 0; k < 8; k++){
    int i = i0 + 8*k;
    if(i < NA_){
      float e = expf(scr[i*4 + hh] - pmax);
      scr[i*4 + hh] = e;
      psum += e;
    }
  }
  #pragma unroll
  for(int st = 4; st < 32; st <<= 1) psum += __shfl_xor(psum, st, 32);
  if(i0 == 0) scr[252 + hh] = psum;
  float a0=0.f, a1=0.f, a2=0.f, a3=0.f;
  for(int i = 0; i < NA_; i++){
    float4 e4 = *(const float4*)&scr[i*4];
    float xv = sx2[i*32 + l];
    a0 += e4.x*xv; a1 += e4.y*xv; a2 += e4.z*xv; a3 += e4.w*xv;
  }
  orow[     l] = eluf(a0 / scr[252]);
  orow[32 + l] = eluf(a1 / scr[253]);
  orow[64 + l] = eluf(a2 / scr[254]);
  orow[96 + l] = eluf(a3 / scr[255]);
}

// gi[t][b][c][n] = (xg@Wih^T)[n][c] + bih[c] + (c<256 ? bhh[c] : 0)
// grid T*B x 512. Each thread: n = tid&63, 16 c's per gate group.
__global__ __launch_bounds__(512, 2) void gi_k(const float* __restrict__ xg,
                                               const float* __restrict__ Wih,
                                               const float* __restrict__ bih,
                                               const float* __restrict__ bhh,
                                               float* __restrict__ gi){
  __shared__ float sxg[64*SHP];
  int tb = blockIdx.x;
  int tid = threadIdx.x;
  const float* xr = xg + (size_t)tb*(N_*H_);
  for(int i = tid; i < N_*H_; i += 512){
    int r = i >> 7, k = i & 127;
    sxg[r*SHP + k] = xr[i];
  }
  __syncthreads();
  int n = tid & 63;
  int g = __builtin_amdgcn_readfirstlane(tid >> 6);   // wave-uniform 0..7
  const float* w0 = Wih + (size_t)(      g*16)*H_;
  const float* w1 = Wih + (size_t)(128 + g*16)*H_;
  const float* w2 = Wih + (size_t)(256 + g*16)*H_;
  float ar[16], az[16], an[16];
  #pragma unroll
  for(int cc = 0; cc < 16; cc++){
    int c = g*16 + cc;
    ar[cc] = bih[c]       + bhh[c];
    az[cc] = bih[128 + c] + bhh[128 + c];
    an[cc] = bih[256 + c];                 // bhn NOT folded (gated by r)
  }
  for(int kc = 0; kc < 16; kc++){
    float hv[8];
    #pragma unroll
    for(int k = 0; k < 8; k++) hv[k] = sxg[n*SHP + kc*8 + k];
    #pragma unroll
    for(int cc = 0; cc < 16; cc++){
      #pragma unroll
      for(int k = 0; k < 8; k++){
        ar[cc] += w0[cc*H_ + kc*8 + k]*hv[k];
        az[cc] += w1[cc*H_ + kc*8 + k]*hv[k];
        an[cc] += w2[cc*H_ + kc*8 + k]*hv[k];
      }
    }
  }
  float* go = gi + (size_t)tb*384*64;
  #pragma unroll
  for(int cc = 0; cc < 16; cc++){
    int c = g*16 + cc;
    go[(      c)*64 + n] = ar[cc];
    go[(128 + c)*64 + n] = az[cc];
    go[(256 + c)*64 + n] = an[cc];
  }
}

// ---------------- persistent per-batch T-loop. grid 32 x 512 ----------------
__global__ __launch_bounds__(512, 2) void loop_k(
    const float* __restrict__ gi_all, const float* __restrict__ h0,
    const float* __restrict__ Whh, const float* __restrict__ bhh,
    const float* __restrict__ W1, const float* __restrict__ b1,
    const float* __restrict__ W2, const float* __restrict__ b2,
    const float* __restrict__ oW, const float* __restrict__ ob,
    float* __restrict__ pred){
  __shared__ float sh[64*SHP];     // h, persists across steps (33 KB)
  __shared__ float sx2[64*33];     // GAT2 fc1 out
  __shared__ float sef[256];       // sender proj + b2
  __shared__ float spr[256];       // receiver proj
  __shared__ float sscr[16*256];   // per-subgroup attention scratch (16 KB)
  __shared__ float sW1[32*H_];     // 16 KB
  __shared__ float sW2t[8*33];
  __shared__ float sb1[32], sob[2], soW[2*H_];
  int tid = threadIdx.x, b = blockIdx.x;

  for(int i = tid; i < N_*H_; i += 512){
    int r = i >> 7, k = i & 127;
    sh[r*SHP + k] = h0[(size_t)b*N_*H_ + i];
  }
  for(int i = tid; i < 32*H_; i += 512) sW1[i] = W1[i];
  if(tid < 256){
    int q = tid >> 5, cc = tid & 31;
    sW2t[q*33 + cc] = W2[(q&3)*64 + ((q < 4) ? 0 : 32) + cc];
  }
  if(tid < 32) sb1[tid] = b1[tid];
  if(tid < 256) soW[tid] = oW[tid];
  if(tid < 2) sob[tid] = ob[tid];
  __syncthreads();

  int n = tid & 63;
  int g = __builtin_amdgcn_readfirstlane(tid >> 6);   // wave-uniform 0..7
  int sgi = tid >> 5, l = tid & 31;
  const float* wr_ = Whh + (size_t)(      g*16)*H_;
  const float* wz_ = Whh + (size_t)(128 + g*16)*H_;
  const float* wn_ = Whh + (size_t)(256 + g*16)*H_;
  float bhn_r[16];
  #pragma unroll
  for(int cc = 0; cc < 16; cc++) bhn_r[cc] = bhh[256 + g*16 + cc];

  for(int t = 0; t < T_; t++){
    // ---- phase A: GRU. Each thread: row n, h-cols g*16..g*16+15 ----
    const float* gip = gi_all + ((size_t)t*B_ + b)*384*64;
    float gr[16], gz[16], gn[16];
    #pragma unroll
    for(int cc = 0; cc < 16; cc++){
      int c = g*16 + cc;
      gr[cc] = gip[(      c)*64 + n];
      gz[cc] = gip[(128 + c)*64 + n];
      gn[cc] = gip[(256 + c)*64 + n];
    }
    float ar[16], az[16], an[16];
    #pragma unroll
    for(int cc = 0; cc < 16; cc++){ ar[cc]=0.f; az[cc]=0.f; an[cc]=0.f; }
    for(int kc = 0; kc < 16; kc++){
      float hv[8];
      #pragma unroll
      for(int k = 0; k < 8; k++) hv[k] = sh[n*SHP + kc*8 + k];
      #pragma unroll
      for(int cc = 0; cc < 16; cc++){
        #pragma unroll
        for(int k = 0; k < 8; k++){
          ar[cc] += wr_[cc*H_ + kc*8 + k]*hv[k];
          az[cc] += wz_[cc*H_ + kc*8 + k]*hv[k];
          an[cc] += wn_[cc*H_ + kc*8 + k]*hv[k];
        }
      }
    }
    float hnew[16];
    #pragma unroll
    for(int cc = 0; cc < 16; cc++){
      float rg = 1.f/(1.f + expf(-(gr[cc] + ar[cc])));
      float zg = 1.f/(1.f + expf(-(gz[cc] + az[cc])));
      float ng = tanhf(gn[cc] + rg*(an[cc] + bhn_r[cc]));
      float hp = sh[n*SHP + g*16 + cc];
      hnew[cc] = (1.f - zg)*ng + zg*hp;
    }
    __syncthreads();
    #pragma unroll
    for(int cc = 0; cc < 16; cc++) sh[n*SHP + g*16 + cc] = hnew[cc];
    __syncthreads();

    // ---- phase B1: fc1. Each thread: row n, cols g*4..g*4+3 ----
    {
      float a[4] = {sb1[g*4], sb1[g*4+1], sb1[g*4+2], sb1[g*4+3]};
      for(int k = 0; k < H_; k++){
        float hv = sh[n*SHP + k];
        #pragma unroll
        for(int q = 0; q < 4; q++) a[q] += sW1[(g*4+q)*H_ + k]*hv;
      }
      #pragma unroll
      for(int q = 0; q < 4; q++) sx2[n*33 + g*4 + q] = a[q];
    }
    __syncthreads();
    // ---- phase B2: fc2 -> sef (sender+b2), spr (receiver) ----
    {
      int rr = tid >> 3, q = tid & 7, hh = q & 3;
      float a = (q < 4) ? b2[hh] : 0.f;
      #pragma unroll
      for(int cc = 0; cc < 32; cc++) a += sx2[rr*33 + cc]*sW2t[q*33 + cc];
      if(q < 4) sef[rr*4 + hh] = a;
      else      spr[rr*4 + hh] = a;
    }
    __syncthreads();

    // ---- phase C: attention, 4 receivers per 32-lane subgroup ----
    float* scr = sscr + sgi*256;
    #pragma unroll
    for(int rep = 0; rep < 4; rep++){
      int j = sgi*4 + rep;
      if(j == NA_){
        #pragma unroll
        for(int q = 0; q < 4; q++) sh[j*SHP + q*32 + l] = 0.f;
      } else {
        float prj = spr[j*4 + (l & 3)];
        int hh = l & 3, i0 = l >> 2;
        float pmax = -1e30f;
        #pragma unroll
        for(int k = 0; k < 8; k++){
          int i = i0 + 8*k;
          if(i < NA_){
            float v = eluf(sef[i*4 + hh] + prj);
            scr[i*4 + hh] = v;
            pmax = fmaxf(pmax, v);
          }
        }
        #pragma unroll
        for(int st = 4; st < 32; st <<= 1) pmax = fmaxf(pmax, __shfl_xor(pmax, st, 32));
        float psum = 0.f;
        #pragma unroll
        for(int k = 0; k < 8; k++){
          int i = i0 + 8*k;
          if(i < NA_){
            float e = expf(scr[i*4 + hh] - pmax);
            scr[i*4 + hh] = e;
            psum += e;
          }
        }
        #pragma unroll
        for(int st = 4; st < 32; st <<= 1) psum += __shfl_xor(psum, st, 32);
        if(i0 == 0) scr[252 + hh] = psum;
        float a0=0.f, a1=0.f, a2=0.f, a3=0.f;
        for(int i = 0; i < NA_; i++){
          float4 e4 = *(const float4*)&scr[i*4];
          float xv = sx2[i*33 + l];
          a0 += e4.x*xv; a1 += e4.y*xv; a2 += e4.z*xv; a3 += e4.w*xv;
        }
        sh[j*SHP +      l] = eluf(a0/scr[252]);
        sh[j*SHP + 32 + l] = eluf(a1/scr[253]);
        sh[j*SHP + 64 + l] = eluf(a2/scr[254]);
        sh[j*SHP + 96 + l] = eluf(a3/scr[255]);
      }
    }
    __syncthreads();
  }

  // ---- final Linear(H->D) ----
  if(tid < 128){
    int nn = tid >> 1, d = tid & 1;
    float a = sob[d];
    #pragma unroll 8
    for(int k = 0; k < H_; k++) a += sh[nn*SHP + k]*soW[d*H_ + k];
    pred[((size_t)b*N_ + nn)*D_ + d] = a;
  }
}

extern "C" void kernel_launch(void* const* d_in, const int* in_sizes, int n_in,
                              void* d_out, int out_size, void* d_ws, size_t ws_size,
                              hipStream_t stream){
  const float* inputs = (const float*)d_in[0];
  const float* hidden = (const float*)d_in[1];
  const float* rn1_W1 = (const float*)d_in[4];
  const float* rn1_b1 = (const float*)d_in[5];
  const float* rn1_W2 = (const float*)d_in[6];
  const float* rn1_b2 = (const float*)d_in[7];
  const float* rn2_W1 = (const float*)d_in[8];
  const float* rn2_b1 = (const float*)d_in[9];
  const float* rn2_W2 = (const float*)d_in[10];
  const float* rn2_b2 = (const float*)d_in[11];
  const float* gWih   = (const float*)d_in[12];
  const float* gWhh   = (const float*)d_in[13];
  const float* gbih   = (const float*)d_in[14];
  const float* gbhh   = (const float*)d_in[15];
  const float* oW     = (const float*)d_in[16];
  const float* ob     = (const float*)d_in[17];
  float* ws = (float*)d_ws;

  gat1_fc<<<T_*B_, 256, 0, stream>>>(inputs, rn1_W1, rn1_b1, rn1_W2, rn1_b2,
                                     ws + OFF_X1, ws + OFF_PS1, ws + OFF_PR1);
  att8<<<T_*B_*8, 256, 0, stream>>>(ws + OFF_X1, ws + OFF_PS1, ws + OFF_PR1,
                                    ws + OFF_XG);
  gi_k<<<T_*B_, 512, 0, stream>>>(ws + OFF_XG, gWih, gbih, gbhh, ws + OFF_GI);
  loop_k<<<B_, 512, 0, stream>>>(ws + OFF_GI, hidden,
                                 gWhh, gbhh,
                                 rn2_W1, rn2_b1, rn2_W2, rn2_b2,
                                 oW, ob, (float*)d_out);
}